// Round 12
// baseline (199.370 us; speedup 1.0000x reference)
//
#include <hip/hip_runtime.h>

#define IMG 224
#define HW (IMG * IMG)
#define TILE 32
#define PAD 4
#define REG 40                 // staged rows/cols per tile
#define RSA 41                 // A-table row stride in float2 (odd -> bank walk)
#define TABA (REG * RSA)       // 1640 float2 per image (ch0,ch1)
#define RSB 44                 // B-table row stride in floats (16B-aligned writes)
#define TABB (REG * RSB)       // 1760 floats per image (ch2)
#define BUFF 10080             // floats per tile buffer: 2*1640*2 + 2*1760
#define TPT 4                  // tiles per block
#define NTILE (49 * 64)        // 3136 logical tiles
#define NBLK (NTILE / TPT)     // 784 blocks; 784 % 8 == 0 -> bijective swizzle
#define NXCD 8

typedef float vf4 __attribute__((ext_vector_type(4)));

struct U3 { float4 a, b, c; };

__device__ __forceinline__ U3 load3(const float* __restrict__ src, int gi) {
    U3 u;
    if (gi >= 0 && gi <= HW - 4) {
        u.a = *(const float4*)(src + gi);
        u.b = *(const float4*)(src + HW + gi);
        u.c = *(const float4*)(src + 2 * HW + gi);
    } else {                        // flat-clamp edge rows (rare)
#pragma unroll
        for (int i = 0; i < 4; ++i) {
            int g = min(max(gi + i, 0), HW - 1);
            ((float*)&u.a)[i] = src[g];
            ((float*)&u.b)[i] = src[HW + g];
            ((float*)&u.c)[i] = src[2 * HW + g];
        }
    }
    return u;
}

__device__ __forceinline__ void writeU(float* __restrict__ base, int img,
                                       int r, int s, const U3& u) {
    float2* dA = (float2*)base + img * TABA + r * RSA + 4 * s;
    dA[0] = make_float2(u.a.x, u.b.x);
    dA[1] = make_float2(u.a.y, u.b.y);
    dA[2] = make_float2(u.a.z, u.b.z);
    dA[3] = make_float2(u.a.w, u.b.w);
    *(float4*)(base + 6560 + img * TABB + r * RSB + 4 * s) = u.c;
}

// consumer: compute one 32x32 tile from the pair-layout buffer (R7-verified)
__device__ __forceinline__ void compute_tile(
    const float* __restrict__ Bf, int x0, int y0, int tx, int ty0,
    vf4 c0v, vf4 c1v, vf4 m1v, vf4 m2v,
    const float* __restrict__ i1n, const float* __restrict__ i2n,
    float* __restrict__ on)
{
    const float2* TA = (const float2*)Bf;
    const float*  TB = Bf + 6560;
    const int xlo = x0 - PAD, ylo = y0 - PAD;
    const int p  = (x0 + tx) * IMG + y0 + ty0;
    const float xf = (float)(x0 + tx);
    float acc0[4], acc1[4], acc2[4];

#pragma unroll
    for (int i = 0; i < 4; ++i) {
        const float yf  = (float)(y0 + ty0 + i);
        const float cc0 = c0v[i], cc1 = c1v[i];
        const float m1i = m1v[i], m2i = m2v[i];
        float r0c, r1c, r2c;

        {   // +C on im1
            float px = xf + cc0, py = yf + cc1;
            float fx = floorf(px), cx = ceilf(px);
            float fy = floorf(py), cy = ceilf(py);
            float wfx = 1.0f - (px - fx), wcx = 1.0f - (cx - px);
            float wfy = 1.0f - (py - fy), wcy = 1.0f - (cy - py);
            float w0 = wfx * wfy, w1 = wcx * wfy;
            float w2 = wfx * wcy, w3 = wcx * wcy;
            int gx0 = (int)fx, gy0 = (int)fy;
            int dx = (int)cx - gx0, dy = (int)cy - gy0;
            int q0 = gx0 - xlo, r0 = gy0 - ylo;
            int in = (q0 >= 0) & (q0 + dx <= REG - 1) &
                     (r0 >= 0) & (r0 + dy <= REG - 1);
            if (__all(in)) {
                int oA = r0 * RSA + q0, oB = r0 * RSB + q0;
                float2 A0 = TA[oA],            A1 = TA[oA + dx];
                float2 A2 = TA[oA + dy * RSA], A3 = TA[oA + dx + dy * RSA];
                float  b0 = TB[oB],            b1 = TB[oB + dx];
                float  b2 = TB[oB + dy * RSB], b3 = TB[oB + dx + dy * RSB];
                r0c = m1i * (w0 * A0.x + w1 * A1.x + w2 * A2.x + w3 * A3.x);
                r1c = m1i * (w0 * A0.y + w1 * A1.y + w2 * A2.y + w3 * A3.y);
                r2c = m1i * (w0 * b0   + w1 * b1   + w2 * b2   + w3 * b3);
            } else {   // rare: beyond PAD -> global clamped gather
                int i0 = min(max(gx0      + IMG * gy0,        0), HW - 1);
                int i1 = min(max(gx0 + dx + IMG * gy0,        0), HW - 1);
                int i2 = min(max(gx0      + IMG * (gy0 + dy), 0), HW - 1);
                int i3 = min(max(gx0 + dx + IMG * (gy0 + dy), 0), HW - 1);
                r0c = m1i * (w0 * i1n[i0] + w1 * i1n[i1] +
                             w2 * i1n[i2] + w3 * i1n[i3]);
                r1c = m1i * (w0 * i1n[HW + i0] + w1 * i1n[HW + i1] +
                             w2 * i1n[HW + i2] + w3 * i1n[HW + i3]);
                r2c = m1i * (w0 * i1n[2 * HW + i0] + w1 * i1n[2 * HW + i1] +
                             w2 * i1n[2 * HW + i2] + w3 * i1n[2 * HW + i3]);
            }
        }
        {   // -C on im2
            float px = xf - cc0, py = yf - cc1;
            float fx = floorf(px), cx = ceilf(px);
            float fy = floorf(py), cy = ceilf(py);
            float wfx = 1.0f - (px - fx), wcx = 1.0f - (cx - px);
            float wfy = 1.0f - (py - fy), wcy = 1.0f - (cy - py);
            float w0 = wfx * wfy, w1 = wcx * wfy;
            float w2 = wfx * wcy, w3 = wcx * wcy;
            int gx0 = (int)fx, gy0 = (int)fy;
            int dx = (int)cx - gx0, dy = (int)cy - gy0;
            int q0 = gx0 - xlo, r0 = gy0 - ylo;
            int in = (q0 >= 0) & (q0 + dx <= REG - 1) &
                     (r0 >= 0) & (r0 + dy <= REG - 1);
            if (__all(in)) {
                const float2* TA2 = TA + TABA;
                const float*  TB2 = TB + TABB;
                int oA = r0 * RSA + q0, oB = r0 * RSB + q0;
                float2 A0 = TA2[oA],            A1 = TA2[oA + dx];
                float2 A2 = TA2[oA + dy * RSA], A3 = TA2[oA + dx + dy * RSA];
                float  b0 = TB2[oB],            b1 = TB2[oB + dx];
                float  b2 = TB2[oB + dy * RSB], b3 = TB2[oB + dx + dy * RSB];
                r0c += m2i * (w0 * A0.x + w1 * A1.x + w2 * A2.x + w3 * A3.x);
                r1c += m2i * (w0 * A0.y + w1 * A1.y + w2 * A2.y + w3 * A3.y);
                r2c += m2i * (w0 * b0   + w1 * b1   + w2 * b2   + w3 * b3);
            } else {
                int i0 = min(max(gx0      + IMG * gy0,        0), HW - 1);
                int i1 = min(max(gx0 + dx + IMG * gy0,        0), HW - 1);
                int i2 = min(max(gx0      + IMG * (gy0 + dy), 0), HW - 1);
                int i3 = min(max(gx0 + dx + IMG * (gy0 + dy), 0), HW - 1);
                r0c += m2i * (w0 * i2n[i0] + w1 * i2n[i1] +
                              w2 * i2n[i2] + w3 * i2n[i3]);
                r1c += m2i * (w0 * i2n[HW + i0] + w1 * i2n[HW + i1] +
                              w2 * i2n[HW + i2] + w3 * i2n[HW + i3]);
                r2c += m2i * (w0 * i2n[2 * HW + i0] + w1 * i2n[2 * HW + i1] +
                              w2 * i2n[2 * HW + i2] + w3 * i2n[2 * HW + i3]);
            }
        }
        acc0[i] = r0c; acc1[i] = r1c; acc2[i] = r2c;
    }

    vf4 s0 = {acc0[0], acc0[1], acc0[2], acc0[3]};
    vf4 s1 = {acc1[0], acc1[1], acc1[2], acc1[3]};
    vf4 s2 = {acc2[0], acc2[1], acc2[2], acc2[3]};
    __builtin_nontemporal_store(s0, (vf4*)(on + p));
    __builtin_nontemporal_store(s1, (vf4*)(on + HW + p));
    __builtin_nontemporal_store(s2, (vf4*)(on + 2 * HW + p));
}

__global__ __launch_bounds__(512, 4) void vm_kernel(
    const float* __restrict__ im1, const float* __restrict__ im2,
    const float* __restrict__ C, const float* __restrict__ M1,
    const float* __restrict__ M2, float* __restrict__ out)
{
    // double-buffered pair layout: 2 x 40,320 B -> 2 blocks/CU (16 waves)
    __shared__ __align__(16) float lds[2 * BUFF];

    // XCD swizzle (verified R7): each XCD gets 98 blocks = 392 tiles = 8 n's.
    const int bid = blockIdx.x;
    const int b   = (bid & (NXCD - 1)) * (NBLK / NXCD) + (bid >> 3);
    const int g0  = b * TPT;
    const int t   = threadIdx.x;

    // consumer pixel mapping (threads 0..255, waves 0-3)
    const int tx  = t >> 3;
    const int ty0 = (t & 7) * 4;

    // tile-0 geometry
    int n0 = g0 / 49, tl0 = g0 - n0 * 49;
    int x00 = (tl0 / 7) * TILE, y00 = (tl0 % 7) * TILE;

    // ---- consumer prologue: C/M for tile 0 (issued first, land under staging)
    vf4 c0c, c1c, m1c, m2c;
    if (t < 256) {
        const float* Cn = C + (size_t)n0 * 2 * HW;
        int p = (x00 + tx) * IMG + y00 + ty0;
        c0c = __builtin_nontemporal_load((const vf4*)(Cn + p));
        c1c = __builtin_nontemporal_load((const vf4*)(Cn + HW + p));
        m1c = __builtin_nontemporal_load((const vf4*)(M1 + (size_t)n0 * HW + p));
        m2c = __builtin_nontemporal_load((const vf4*)(M2 + (size_t)n0 * HW + p));
    }

    // ---- all-thread staging of tile 0 into buf0 (800 units over 512 threads)
    {
        const float* i1n = im1 + (size_t)n0 * 3 * HW;
        const float* i2n = im2 + (size_t)n0 * 3 * HW;
        int gb = (x00 - PAD) + IMG * (y00 - PAD);
#pragma unroll
        for (int kk = 0; kk < 2; ++kk) {
            int e2 = t + 512 * kk;
            if (e2 < 800) {                 // kk=1 partial (t<288)
                int img = (e2 >= 400);
                int e = e2 - 400 * img;
                int r = e / 10, s = e - 10 * r;
                U3 u = load3(img ? i2n : i1n, gb + IMG * r + 4 * s);
                writeU(lds, img, r, s, u);
            }
        }
    }
    __syncthreads();

#pragma unroll 1
    for (int k = 0; k < TPT; ++k) {
        float* bufC = lds + (k & 1) * BUFF;
        float* bufN = lds + ((k + 1) & 1) * BUFF;
        int gk = g0 + k;
        int nk = gk / 49, tlk = gk - nk * 49;
        int x0 = (tlk / 7) * TILE, y0 = (tlk % 7) * TILE;

        if (t < 256) {
            // ---- consumer: prefetch C/M for tile k+1, then compute tile k
            vf4 c0n, c1n, m1n, m2n;
            if (k + 1 < TPT) {
                int gn = gk + 1;
                int nn = gn / 49, tln = gn - nn * 49;
                int xn = (tln / 7) * TILE, yn = (tln % 7) * TILE;
                const float* Cn = C + (size_t)nn * 2 * HW;
                int pn = (xn + tx) * IMG + yn + ty0;
                c0n = __builtin_nontemporal_load((const vf4*)(Cn + pn));
                c1n = __builtin_nontemporal_load((const vf4*)(Cn + HW + pn));
                m1n = __builtin_nontemporal_load((const vf4*)(M1 + (size_t)nn * HW + pn));
                m2n = __builtin_nontemporal_load((const vf4*)(M2 + (size_t)nn * HW + pn));
            }
            const float* i1n = im1 + (size_t)nk * 3 * HW;
            const float* i2n = im2 + (size_t)nk * 3 * HW;
            compute_tile(bufC, x0, y0, tx, ty0, c0c, c1c, m1c, m2c,
                         i1n, i2n, out + (size_t)nk * 3 * HW);
            if (k + 1 < TPT) { c0c = c0n; c1c = c1n; m1c = m1n; m2c = m2n; }
        } else {
            // ---- producer: stage tile k+1 into bufN (overlaps compute above)
            if (k + 1 < TPT) {
                int gn = gk + 1;
                int nn = gn / 49, tln = gn - nn * 49;
                int xn = (tln / 7) * TILE, yn = (tln % 7) * TILE;
                const float* i1n = im1 + (size_t)nn * 3 * HW;
                const float* i2n = im2 + (size_t)nn * 3 * HW;
                int gb = (xn - PAD) + IMG * (yn - PAD);
                int u = t - 256;
                int r1 = u / 10, s1 = u - 10 * r1;                // unit u (<400)
                int r2 = (u + 256) / 10, s2 = (u + 256) - 10 * r2; // unit u+256
                bool h2 = (u < 144);
                // issue all loads first (max MLP), then the dependent writes
                U3 a1 = load3(i1n, gb + IMG * r1 + 4 * s1);
                U3 b1 = load3(i2n, gb + IMG * r1 + 4 * s1);
                U3 a2, b2;
                if (h2) {
                    a2 = load3(i1n, gb + IMG * r2 + 4 * s2);
                    b2 = load3(i2n, gb + IMG * r2 + 4 * s2);
                }
                writeU(bufN, 0, r1, s1, a1);
                writeU(bufN, 1, r1, s1, b1);
                if (h2) {
                    writeU(bufN, 0, r2, s2, a2);
                    writeU(bufN, 1, r2, s2, b2);
                }
            }
        }
        __syncthreads();
    }
}

extern "C" void kernel_launch(void* const* d_in, const int* in_sizes, int n_in,
                              void* d_out, int out_size, void* d_ws, size_t ws_size,
                              hipStream_t stream) {
    const float* im1 = (const float*)d_in[0];
    const float* im2 = (const float*)d_in[1];
    const float* C   = (const float*)d_in[2];
    const float* M1  = (const float*)d_in[3];
    const float* M2  = (const float*)d_in[4];
    float* out = (float*)d_out;
    vm_kernel<<<dim3(NBLK), 512, 0, stream>>>(im1, im2, C, M1, M2, out);
}

// Round 13
// 175.864 us; speedup vs baseline: 1.1337x; 1.1337x over previous
//
#include <hip/hip_runtime.h>

#define IMG 224
#define HW (IMG * IMG)
#define TILE 32
#define PAD 4
#define REG (TILE + 2 * PAD)   // 40: staged rows/cols per tile
#define RSA 41                 // A-table row stride in float2 units (odd)
#define TABA (REG * RSA)       // 1640 float2 per image (ch0,ch1 packed)
#define RSB 44                 // B-table row stride in floats (mult of 4)
#define TABB (REG * RSB)       // 1760 floats per image (ch2)

#define NXCD 8
#define NWG  (49 * 64)         // 3136 blocks, % 8 == 0 -> bijective swizzle

typedef float vf2 __attribute__((ext_vector_type(2)));

__global__ __launch_bounds__(512, 8) void vm_kernel(
    const float* __restrict__ im1, const float* __restrict__ im2,
    const float* __restrict__ C, const float* __restrict__ M1,
    const float* __restrict__ M2, float* __restrict__ out)
{
    // Pair layout (R7-verified): 40,320 B -> 4 blocks/CU x 8 waves = 32 waves
    // resident (8/SIMD, 3x the 256-thread variant) at IDENTICAL bytes/tiles.
    __shared__ float2 tabA[2 * TABA];
    __shared__ float  tabB[2 * TABB];

    // XCD-aware swizzle (verified R7: FETCH 150 -> 63 MB)
    const int bid     = blockIdx.x;
    const int logical = (bid & (NXCD - 1)) * (NWG / NXCD) + (bid >> 3);
    const int n       = logical / 49;
    const int tile    = logical - n * 49;

    const int x0   = (tile / 7) * TILE;
    const int y0   = (tile % 7) * TILE;
    const int t    = threadIdx.x;
    const int xlo  = x0 - PAD;
    const int ylo  = y0 - PAD;
    const int gbase = xlo + IMG * ylo;

    const float* i1n = im1 + (size_t)n * 3 * HW;
    const float* i2n = im2 + (size_t)n * 3 * HW;
    const float* Cn  = C  + (size_t)n * 2 * HW;
    const float* M1n = M1 + (size_t)n * HW;
    const float* M2n = M2 + (size_t)n * HW;

    // ---- C/M first (land under staging). Thread owns 2 consecutive ty.
    const int tx  = t >> 4;                // 0..31 (slow coord, p / 224)
    const int ty0 = (t & 15) * 2;          // 0,2,..,30 (fast coord base)
    const int p   = (x0 + tx) * IMG + (y0 + ty0);

    const vf2 c0v = __builtin_nontemporal_load((const vf2*)(Cn + p));
    const vf2 c1v = __builtin_nontemporal_load((const vf2*)(Cn + HW + p));
    const vf2 m1v = __builtin_nontemporal_load((const vf2*)(M1n + p));
    const vf2 m2v = __builtin_nontemporal_load((const vf2*)(M2n + p));

    // ---- staging: 800 units (2 img x 400) over 512 threads, <=2 per thread.
    //      Unit = 4 consecutive pixels of one row: 3 float4 global loads,
    //      4 ds_write_b64 (A) + 1 ds_write_b128 (B).
#pragma unroll
    for (int kk = 0; kk < 2; ++kk) {
        int img, e;
        bool act;
        if (kk == 0) { img = (t >= 400); e = t - 400 * img; act = true; }
        else         { img = 1;          e = t + 112;       act = (t < 288); }
        if (act) {
            const float* src = img ? i2n : i1n;
            int r = e / 10, s = e - r * 10;
            int gi = gbase + IMG * r + 4 * s;
            float4 a, b, c;
            if (gi >= 0 && gi <= HW - 4) {
                a = *(const float4*)(src + gi);
                b = *(const float4*)(src + HW + gi);
                c = *(const float4*)(src + 2 * HW + gi);
            } else {                    // flat-clamp edge rows (rare)
#pragma unroll
                for (int i = 0; i < 4; ++i) {
                    int g = min(max(gi + i, 0), HW - 1);
                    ((float*)&a)[i] = src[g];
                    ((float*)&b)[i] = src[HW + g];
                    ((float*)&c)[i] = src[2 * HW + g];
                }
            }
            float2* dA = tabA + img * TABA + r * RSA + 4 * s;
            dA[0] = make_float2(a.x, b.x);
            dA[1] = make_float2(a.y, b.y);
            dA[2] = make_float2(a.z, b.z);
            dA[3] = make_float2(a.w, b.w);
            *(float4*)(tabB + img * TABB + r * RSB + 4 * s) = c;
        }
    }

    __syncthreads();                       // the ONLY barrier

    // ---- phase 2: 2 pixels per thread; per tap one ds_read_b64 (ch0,ch1)
    //      + one ds_read_b32 (ch2).
    const float xf = (float)(x0 + tx);
    float acc0[2], acc1[2], acc2[2];

#pragma unroll
    for (int i = 0; i < 2; ++i) {
        const float yf  = (float)(y0 + ty0 + i);
        const float cc0 = c0v[i];
        const float cc1 = c1v[i];
        const float m1i = m1v[i];
        const float m2i = m2v[i];
        float r0c, r1c, r2c;

        {   // +C on im1
            float px = xf + cc0, py = yf + cc1;
            float fx = floorf(px), cx = ceilf(px);
            float fy = floorf(py), cy = ceilf(py);
            float wfx = 1.0f - (px - fx), wcx = 1.0f - (cx - px);
            float wfy = 1.0f - (py - fy), wcy = 1.0f - (cy - py);
            float w0 = wfx * wfy, w1 = wcx * wfy;
            float w2 = wfx * wcy, w3 = wcx * wcy;
            int gx0 = (int)fx, gy0 = (int)fy;
            int dx = (int)cx - gx0, dy = (int)cy - gy0;
            int q0 = gx0 - xlo, r0 = gy0 - ylo;
            int in = (q0 >= 0) & (q0 + dx <= REG - 1) &
                     (r0 >= 0) & (r0 + dy <= REG - 1);
            if (__all(in)) {
                int oA = r0 * RSA + q0;
                int oB = r0 * RSB + q0;
                float2 a0 = tabA[oA],            a1 = tabA[oA + dx];
                float2 a2 = tabA[oA + dy * RSA], a3 = tabA[oA + dx + dy * RSA];
                float  b0 = tabB[oB],            b1 = tabB[oB + dx];
                float  b2 = tabB[oB + dy * RSB], b3 = tabB[oB + dx + dy * RSB];
                r0c = m1i * (w0 * a0.x + w1 * a1.x + w2 * a2.x + w3 * a3.x);
                r1c = m1i * (w0 * a0.y + w1 * a1.y + w2 * a2.y + w3 * a3.y);
                r2c = m1i * (w0 * b0   + w1 * b1   + w2 * b2   + w3 * b3);
            } else {   // rare: displacement beyond PAD -> global clamped gather
                int i0 = min(max(gx0      + IMG * gy0,        0), HW - 1);
                int i1 = min(max(gx0 + dx + IMG * gy0,        0), HW - 1);
                int i2 = min(max(gx0      + IMG * (gy0 + dy), 0), HW - 1);
                int i3 = min(max(gx0 + dx + IMG * (gy0 + dy), 0), HW - 1);
                r0c = m1i * (w0 * i1n[i0] + w1 * i1n[i1] +
                             w2 * i1n[i2] + w3 * i1n[i3]);
                r1c = m1i * (w0 * i1n[HW + i0] + w1 * i1n[HW + i1] +
                             w2 * i1n[HW + i2] + w3 * i1n[HW + i3]);
                r2c = m1i * (w0 * i1n[2 * HW + i0] + w1 * i1n[2 * HW + i1] +
                             w2 * i1n[2 * HW + i2] + w3 * i1n[2 * HW + i3]);
            }
        }
        {   // -C on im2
            float px = xf - cc0, py = yf - cc1;
            float fx = floorf(px), cx = ceilf(px);
            float fy = floorf(py), cy = ceilf(py);
            float wfx = 1.0f - (px - fx), wcx = 1.0f - (cx - px);
            float wfy = 1.0f - (py - fy), wcy = 1.0f - (cy - py);
            float w0 = wfx * wfy, w1 = wcx * wfy;
            float w2 = wfx * wcy, w3 = wcx * wcy;
            int gx0 = (int)fx, gy0 = (int)fy;
            int dx = (int)cx - gx0, dy = (int)cy - gy0;
            int q0 = gx0 - xlo, r0 = gy0 - ylo;
            int in = (q0 >= 0) & (q0 + dx <= REG - 1) &
                     (r0 >= 0) & (r0 + dy <= REG - 1);
            if (__all(in)) {
                const float2* TA = tabA + TABA;
                const float*  TB = tabB + TABB;
                int oA = r0 * RSA + q0;
                int oB = r0 * RSB + q0;
                float2 a0 = TA[oA],            a1 = TA[oA + dx];
                float2 a2 = TA[oA + dy * RSA], a3 = TA[oA + dx + dy * RSA];
                float  b0 = TB[oB],            b1 = TB[oB + dx];
                float  b2 = TB[oB + dy * RSB], b3 = TB[oB + dx + dy * RSB];
                r0c += m2i * (w0 * a0.x + w1 * a1.x + w2 * a2.x + w3 * a3.x);
                r1c += m2i * (w0 * a0.y + w1 * a1.y + w2 * a2.y + w3 * a3.y);
                r2c += m2i * (w0 * b0   + w1 * b1   + w2 * b2   + w3 * b3);
            } else {
                int i0 = min(max(gx0      + IMG * gy0,        0), HW - 1);
                int i1 = min(max(gx0 + dx + IMG * gy0,        0), HW - 1);
                int i2 = min(max(gx0      + IMG * (gy0 + dy), 0), HW - 1);
                int i3 = min(max(gx0 + dx + IMG * (gy0 + dy), 0), HW - 1);
                r0c += m2i * (w0 * i2n[i0] + w1 * i2n[i1] +
                              w2 * i2n[i2] + w3 * i2n[i3]);
                r1c += m2i * (w0 * i2n[HW + i0] + w1 * i2n[HW + i1] +
                              w2 * i2n[HW + i2] + w3 * i2n[HW + i3]);
                r2c += m2i * (w0 * i2n[2 * HW + i0] + w1 * i2n[2 * HW + i1] +
                              w2 * i2n[2 * HW + i2] + w3 * i2n[2 * HW + i3]);
            }
        }
        acc0[i] = r0c; acc1[i] = r1c; acc2[i] = r2c;
    }

    // coalesced non-temporal float2 stores (lanes consecutive in ty0)
    float* on = out + (size_t)n * 3 * HW;
    vf2 s0 = {acc0[0], acc0[1]};
    vf2 s1 = {acc1[0], acc1[1]};
    vf2 s2 = {acc2[0], acc2[1]};
    __builtin_nontemporal_store(s0, (vf2*)(on + p));
    __builtin_nontemporal_store(s1, (vf2*)(on + HW + p));
    __builtin_nontemporal_store(s2, (vf2*)(on + 2 * HW + p));
}

extern "C" void kernel_launch(void* const* d_in, const int* in_sizes, int n_in,
                              void* d_out, int out_size, void* d_ws, size_t ws_size,
                              hipStream_t stream) {
    const float* im1 = (const float*)d_in[0];
    const float* im2 = (const float*)d_in[1];
    const float* C   = (const float*)d_in[2];
    const float* M1  = (const float*)d_in[3];
    const float* M2  = (const float*)d_in[4];
    float* out = (float*)d_out;
    vm_kernel<<<dim3(NWG), 512, 0, stream>>>(im1, im2, C, M1, M2, out);
}

// Round 14
// 169.472 us; speedup vs baseline: 1.1764x; 1.0377x over previous
//
#include <hip/hip_runtime.h>

#define IMG 224
#define HW (IMG * IMG)
#define TLY 32                 // tile extent y (fast output coord)
#define PAD 4
#define REGY 40                // staged rows (y)
#define RSA 73                 // A-table row stride in float2 (odd -> bank walk)
#define TABA (REGY * RSA)      // 2920 float2 per image (ch0,ch1)
#define RSB 76                 // B-table row stride in floats (mult of 4)
#define TABB (REGY * RSB)      // 3040 floats per image (ch2)

#define NXCD 8
#define NBLK 1792              // 4 x-tiles x 7 y-tiles x 64 n ; % 8 == 0

typedef float vf4 __attribute__((ext_vector_type(4)));

__device__ __forceinline__ void stage_unit(
    const float* __restrict__ src, float2* __restrict__ TA,
    float* __restrict__ TB, int gbase, int r, int s)
{
    int gi = gbase + IMG * r + 4 * s;
    float4 a, b, c;
    if (gi >= 0 && gi <= HW - 4) {
        a = *(const float4*)(src + gi);
        b = *(const float4*)(src + HW + gi);
        c = *(const float4*)(src + 2 * HW + gi);
    } else {                        // flat-clamp edge rows (rare)
#pragma unroll
        for (int i = 0; i < 4; ++i) {
            int g = min(max(gi + i, 0), HW - 1);
            ((float*)&a)[i] = src[g];
            ((float*)&b)[i] = src[HW + g];
            ((float*)&c)[i] = src[2 * HW + g];
        }
    }
    float2* dA = TA + r * RSA + 4 * s;
    dA[0] = make_float2(a.x, b.x);
    dA[1] = make_float2(a.y, b.y);
    dA[2] = make_float2(a.z, b.z);
    dA[3] = make_float2(a.w, b.w);
    *(float4*)(TB + r * RSB + 4 * s) = c;   // (r*76+4s) % 4 == 0
}

template <int SU>   // staging units per row: 18 (w=64) or 10 (w=32)
__device__ __forceinline__ void stage_all(
    const float* __restrict__ i1n, const float* __restrict__ i2n,
    float2* __restrict__ tabA, float* __restrict__ tabB, int gbase, int t)
{
    const int upi   = REGY * SU;        // units per image
    const int units = 2 * upi;
#pragma unroll
    for (int kk = 0; kk < 3; ++kk) {
        int e = t + 512 * kk;
        if (e < units) {
            int img = (e >= upi);
            int e2  = e - img * upi;
            int r = e2 / SU, s = e2 - r * SU;
            stage_unit(img ? i2n : i1n, tabA + img * TABA,
                       tabB + img * TABB, gbase, r, s);
        }
    }
}

__global__ __launch_bounds__(512, 4) void vm_kernel(
    const float* __restrict__ im1, const float* __restrict__ im2,
    const float* __restrict__ C, const float* __restrict__ M1,
    const float* __restrict__ M2, float* __restrict__ out)
{
    // 64x32 tile (ragged last x-tile =32): staged region <=40 rows x 72 cols.
    // Pair layout: 2*(2920*8 + 3040*4) = 71,040 B -> 2 blocks/CU.
    __shared__ float2 tabA[2 * TABA];
    __shared__ float  tabB[2 * TABB];

    // XCD swizzle (verified R7): 224 consecutive logicals per XCD = 8 n's.
    const int bid     = blockIdx.x;
    const int logical = (bid & (NXCD - 1)) * (NBLK / NXCD) + (bid >> 3);
    const int n       = logical / 28;
    const int tile    = logical - n * 28;   // 4 x-tiles x 7 y-tiles
    const int xt      = tile / 7;
    const int yt      = tile - xt * 7;
    const int x0      = xt * 64;
    const int y0      = yt * TLY;
    const int w       = (xt == 3) ? 32 : 64;     // ragged last x-tile
    const int cols    = w + 2 * PAD;             // 72 or 40 staged cols

    const int t    = threadIdx.x;
    const int xlo  = x0 - PAD;
    const int ylo  = y0 - PAD;
    const int gbase = xlo + IMG * ylo;

    const float* i1n = im1 + (size_t)n * 3 * HW;
    const float* i2n = im2 + (size_t)n * 3 * HW;
    const float* Cn  = C  + (size_t)n * 2 * HW;
    const float* M1n = M1 + (size_t)n * HW;
    const float* M2n = M2 + (size_t)n * HW;

    // ---- C/M first (land under staging). Wave-uniform activity: tx<w.
    const int tx  = t >> 3;                // 0..63 (slow coord, p / 224)
    const int ty0 = (t & 7) * 4;           // 0,4,..,28 (fast coord base)
    const bool act = (tx < w);             // uniform per wave (8 tx per wave)
    const int p   = (x0 + tx) * IMG + (y0 + ty0);

    vf4 c0v, c1v, m1v, m2v;
    if (act) {
        c0v = __builtin_nontemporal_load((const vf4*)(Cn + p));
        c1v = __builtin_nontemporal_load((const vf4*)(Cn + HW + p));
        m1v = __builtin_nontemporal_load((const vf4*)(M1n + p));
        m2v = __builtin_nontemporal_load((const vf4*)(M2n + p));
    }

    // ---- staging (R7-verified unit code; template fixes the div constant)
    if (w == 64) stage_all<18>(i1n, i2n, tabA, tabB, gbase, t);
    else         stage_all<10>(i1n, i2n, tabA, tabB, gbase, t);

    __syncthreads();                       // the ONLY barrier

    if (act) {
        // ---- 4 px/thread; per tap one ds_read_b64 (ch0,ch1) + one b32 (ch2)
        const float xf = (float)(x0 + tx);
        float acc0[4], acc1[4], acc2[4];

#pragma unroll
        for (int i = 0; i < 4; ++i) {
            const float yf  = (float)(y0 + ty0 + i);
            const float cc0 = c0v[i];
            const float cc1 = c1v[i];
            const float m1i = m1v[i];
            const float m2i = m2v[i];
            float r0c, r1c, r2c;

            {   // +C on im1
                float px = xf + cc0, py = yf + cc1;
                float fx = floorf(px), cx = ceilf(px);
                float fy = floorf(py), cy = ceilf(py);
                float wfx = 1.0f - (px - fx), wcx = 1.0f - (cx - px);
                float wfy = 1.0f - (py - fy), wcy = 1.0f - (cy - py);
                float w0 = wfx * wfy, w1 = wcx * wfy;
                float w2 = wfx * wcy, w3 = wcx * wcy;
                int gx0 = (int)fx, gy0 = (int)fy;
                int dx = (int)cx - gx0, dy = (int)cy - gy0;
                int q0 = gx0 - xlo, r0 = gy0 - ylo;
                int in = (q0 >= 0) & (q0 + dx <= cols - 1) &
                         (r0 >= 0) & (r0 + dy <= REGY - 1);
                if (__all(in)) {
                    int oA = r0 * RSA + q0;
                    int oB = r0 * RSB + q0;
                    float2 a0 = tabA[oA],            a1 = tabA[oA + dx];
                    float2 a2 = tabA[oA + dy * RSA], a3 = tabA[oA + dx + dy * RSA];
                    float  b0 = tabB[oB],            b1 = tabB[oB + dx];
                    float  b2 = tabB[oB + dy * RSB], b3 = tabB[oB + dx + dy * RSB];
                    r0c = m1i * (w0 * a0.x + w1 * a1.x + w2 * a2.x + w3 * a3.x);
                    r1c = m1i * (w0 * a0.y + w1 * a1.y + w2 * a2.y + w3 * a3.y);
                    r2c = m1i * (w0 * b0   + w1 * b1   + w2 * b2   + w3 * b3);
                } else {   // rare: beyond PAD -> global clamped gather
                    int i0 = min(max(gx0      + IMG * gy0,        0), HW - 1);
                    int i1 = min(max(gx0 + dx + IMG * gy0,        0), HW - 1);
                    int i2 = min(max(gx0      + IMG * (gy0 + dy), 0), HW - 1);
                    int i3 = min(max(gx0 + dx + IMG * (gy0 + dy), 0), HW - 1);
                    r0c = m1i * (w0 * i1n[i0] + w1 * i1n[i1] +
                                 w2 * i1n[i2] + w3 * i1n[i3]);
                    r1c = m1i * (w0 * i1n[HW + i0] + w1 * i1n[HW + i1] +
                                 w2 * i1n[HW + i2] + w3 * i1n[HW + i3]);
                    r2c = m1i * (w0 * i1n[2 * HW + i0] + w1 * i1n[2 * HW + i1] +
                                 w2 * i1n[2 * HW + i2] + w3 * i1n[2 * HW + i3]);
                }
            }
            {   // -C on im2
                float px = xf - cc0, py = yf - cc1;
                float fx = floorf(px), cx = ceilf(px);
                float fy = floorf(py), cy = ceilf(py);
                float wfx = 1.0f - (px - fx), wcx = 1.0f - (cx - px);
                float wfy = 1.0f - (py - fy), wcy = 1.0f - (cy - py);
                float w0 = wfx * wfy, w1 = wcx * wfy;
                float w2 = wfx * wcy, w3 = wcx * wcy;
                int gx0 = (int)fx, gy0 = (int)fy;
                int dx = (int)cx - gx0, dy = (int)cy - gy0;
                int q0 = gx0 - xlo, r0 = gy0 - ylo;
                int in = (q0 >= 0) & (q0 + dx <= cols - 1) &
                         (r0 >= 0) & (r0 + dy <= REGY - 1);
                if (__all(in)) {
                    const float2* TA = tabA + TABA;
                    const float*  TB = tabB + TABB;
                    int oA = r0 * RSA + q0;
                    int oB = r0 * RSB + q0;
                    float2 a0 = TA[oA],            a1 = TA[oA + dx];
                    float2 a2 = TA[oA + dy * RSA], a3 = TA[oA + dx + dy * RSA];
                    float  b0 = TB[oB],            b1 = TB[oB + dx];
                    float  b2 = TB[oB + dy * RSB], b3 = TB[oB + dx + dy * RSB];
                    r0c += m2i * (w0 * a0.x + w1 * a1.x + w2 * a2.x + w3 * a3.x);
                    r1c += m2i * (w0 * a0.y + w1 * a1.y + w2 * a2.y + w3 * a3.y);
                    r2c += m2i * (w0 * b0   + w1 * b1   + w2 * b2   + w3 * b3);
                } else {
                    int i0 = min(max(gx0      + IMG * gy0,        0), HW - 1);
                    int i1 = min(max(gx0 + dx + IMG * gy0,        0), HW - 1);
                    int i2 = min(max(gx0      + IMG * (gy0 + dy), 0), HW - 1);
                    int i3 = min(max(gx0 + dx + IMG * (gy0 + dy), 0), HW - 1);
                    r0c += m2i * (w0 * i2n[i0] + w1 * i2n[i1] +
                                  w2 * i2n[i2] + w3 * i2n[i3]);
                    r1c += m2i * (w0 * i2n[HW + i0] + w1 * i2n[HW + i1] +
                                  w2 * i2n[HW + i2] + w3 * i2n[HW + i3]);
                    r2c += m2i * (w0 * i2n[2 * HW + i0] + w1 * i2n[2 * HW + i1] +
                                  w2 * i2n[2 * HW + i2] + w3 * i2n[2 * HW + i3]);
                }
            }
            acc0[i] = r0c; acc1[i] = r1c; acc2[i] = r2c;
        }

        // coalesced non-temporal float4 stores
        float* on = out + (size_t)n * 3 * HW;
        vf4 s0 = {acc0[0], acc0[1], acc0[2], acc0[3]};
        vf4 s1 = {acc1[0], acc1[1], acc1[2], acc1[3]};
        vf4 s2 = {acc2[0], acc2[1], acc2[2], acc2[3]};
        __builtin_nontemporal_store(s0, (vf4*)(on + p));
        __builtin_nontemporal_store(s1, (vf4*)(on + HW + p));
        __builtin_nontemporal_store(s2, (vf4*)(on + 2 * HW + p));
    }
}

extern "C" void kernel_launch(void* const* d_in, const int* in_sizes, int n_in,
                              void* d_out, int out_size, void* d_ws, size_t ws_size,
                              hipStream_t stream) {
    const float* im1 = (const float*)d_in[0];
    const float* im2 = (const float*)d_in[1];
    const float* C   = (const float*)d_in[2];
    const float* M1  = (const float*)d_in[3];
    const float* M2  = (const float*)d_in[4];
    float* out = (float*)d_out;
    vm_kernel<<<dim3(NBLK), 512, 0, stream>>>(im1, im2, C, M1, M2, out);
}